// Round 1
// baseline (317.762 us; speedup 1.0000x reference)
//
#include <hip/hip_runtime.h>
#include <hip/hip_bf16.h>

// CaMLoss fused forward for MI355X (gfx950).
// B=4096, D=2048, C=1024 (derived from in_sizes; assumes D multiple of 256,
// B,C multiples of 128, D multiple of 64).

typedef __attribute__((ext_vector_type(8))) short short8;
typedef __attribute__((ext_vector_type(4))) float f32x4;

#define BIGF 1e6f
#define EPSC 1e-12f
#define MAXDD 16   // supports D up to 4096 for the per-thread register rows

__device__ __forceinline__ float bf2f(unsigned short u){
  unsigned int x = ((unsigned int)u) << 16;
  return __uint_as_float(x);
}
__device__ __forceinline__ unsigned short f2bf(float f){
  __hip_bfloat16 h = __float2bfloat16(f);
  return *reinterpret_cast<unsigned short*>(&h);
}

__device__ __forceinline__ float block_reduce_sum(float v){
  __shared__ float red[4];
  int tid = threadIdx.x;
  __syncthreads();                       // protect red from previous use
  #pragma unroll
  for (int s = 32; s; s >>= 1) v += __shfl_xor(v, s);
  if ((tid & 63) == 0) red[tid >> 6] = v;
  __syncthreads();
  return red[0] + red[1] + red[2] + red[3];
}

// ---------------- init per-row stats + class counters ----------------
__global__ void k_init(unsigned* mn0, unsigned* mx0, unsigned* fl0,
                       unsigned* mn1, unsigned* mx1, unsigned* fl1,
                       int* cnt, int B, int C){
  int i = blockIdx.x * blockDim.x + threadIdx.x;
  unsigned bigbits = __float_as_uint(BIGF);
  if (i < B){
    mn0[i] = bigbits; mx0[i] = 0u; fl0[i] = 0u;
    mn1[i] = bigbits; mx1[i] = 0u; fl1[i] = 0u;
  }
  if (i < C) cnt[i] = 0;
}

// ---------------- deterministic per-class member lists ----------------
__global__ void k_list(const int* __restrict__ labels, int* cnt,
                       int* members, int B, int MMAX){
  extern __shared__ int slab[];
  for (int j = threadIdx.x; j < B; j += blockDim.x) slab[j] = labels[j];
  __syncthreads();
  int i = blockIdx.x * blockDim.x + threadIdx.x;
  if (i >= B) return;
  int c = slab[i];
  atomicAdd(&cnt[c], 1);
  int rank = 0;
  for (int j = 0; j < i; ++j) rank += (slab[j] == c) ? 1 : 0;
  if (rank < MMAX) members[c * MMAX + rank] = i;   // rank order => deterministic
}

// ---------------- normalize embeddings -> bf16 + xx ----------------
__global__ __launch_bounds__(256) void k_norm_emb(const float* __restrict__ emb,
    unsigned short* __restrict__ enb, float* __restrict__ exx, int D){
  int i = blockIdx.x, tid = threadIdx.x;
  int DD = D >> 8;
  const float* row = emb + (size_t)i * D;
  float v[MAXDD];
  float ss = 0.f;
  for (int dd = 0; dd < DD; ++dd){ float x = row[dd * 256 + tid]; v[dd] = x; ss += x * x; }
  float tot = block_reduce_sum(ss);
  float inv = 1.f / (sqrtf(tot) + EPSC);
  unsigned short* orow = enb + (size_t)i * D;
  for (int dd = 0; dd < DD; ++dd) orow[dd * 256 + tid] = f2bf(v[dd] * inv);
  if (tid == 0) exx[i] = tot * inv * inv;
}

// ---------------- centers: update + normalize -> bf16 + xx ----------------
__global__ __launch_bounds__(256) void k_centers(const float* __restrict__ emb,
    const float* __restrict__ cval, const float* __restrict__ ccnt,
    const int* __restrict__ cnt, const int* __restrict__ members,
    unsigned short* __restrict__ cnb, float* __restrict__ cxx, int D, int MMAX){
  int c = blockIdx.x, tid = threadIdx.x;
  int DD = D >> 8;
  int n = cnt[c], m = n < MMAX ? n : MMAX;
  float acc[MAXDD];
  for (int dd = 0; dd < DD; ++dd) acc[dd] = 0.f;
  for (int e = 0; e < m; ++e){                       // ascending-index order
    const float* row = emb + (size_t)members[c * MMAX + e] * D;
    for (int dd = 0; dd < DD; ++dd) acc[dd] += row[dd * 256 + tid];
  }
  float cf = (float)n;
  float cen[MAXDD];
  float ss = 0.f;
  for (int dd = 0; dd < DD; ++dd){
    int d = dd * 256 + tid;
    float uc = ccnt[(size_t)c * D + d] + cf;
    float vv = cval[(size_t)c * D + d] + acc[dd];
    float ce = (uc > 0.f) ? (vv / fmaxf(uc, 1.f)) : 0.f;
    cen[dd] = ce; ss += ce * ce;
  }
  float tot = block_reduce_sum(ss);
  float inv = 1.f / (sqrtf(tot) + EPSC);
  for (int dd = 0; dd < DD; ++dd)
    cnb[(size_t)c * D + dd * 256 + tid] = f2bf(cen[dd] * inv);
  if (tid == 0) cxx[c] = tot * inv * inv;
}

// ---------------- hardest positive per row ----------------
__global__ __launch_bounds__(256) void k_hpos(const unsigned short* __restrict__ enb,
    const unsigned short* __restrict__ cnb, const float* __restrict__ exx,
    const float* __restrict__ cxx, const int* __restrict__ labels,
    const int* __restrict__ cnt, const int* __restrict__ members,
    float* __restrict__ hpos, int D, int MMAX){
  int i = blockIdx.x, tid = threadIdx.x;
  int DD = D >> 8;
  int li = labels[i];
  const unsigned short* arow = enb + (size_t)i * D;
  float av[MAXDD];
  for (int dd = 0; dd < DD; ++dd) av[dd] = bf2f(arow[dd * 256 + tid]);
  float xi = exx[i];
  float hp = 0.f;                                   // max with zeros (masked)
  int m = cnt[li] < MMAX ? cnt[li] : MMAX;
  for (int e = 0; e < m; ++e){
    int j = members[li * MMAX + e];
    if (j == i) continue;                           // uniform across block
    const unsigned short* brow = enb + (size_t)j * D;
    float p = 0.f;
    for (int dd = 0; dd < DD; ++dd) p += av[dd] * bf2f(brow[dd * 256 + tid]);
    float dot = block_reduce_sum(p);
    float d2 = xi + exx[j] - 2.f * dot;
    hp = fmaxf(hp, sqrtf(fmaxf(d2, EPSC)));
  }
  {                                                 // own-class center
    const unsigned short* brow = cnb + (size_t)li * D;
    float p = 0.f;
    for (int dd = 0; dd < DD; ++dd) p += av[dd] * bf2f(brow[dd * 256 + tid]);
    float dot = block_reduce_sum(p);
    float d2 = xi + cxx[li] - 2.f * dot;
    hp = fmaxf(hp, sqrtf(fmaxf(d2, EPSC)));
  }
  if (tid == 0) hpos[i] = hp;
}

// ---------------- fused distance pass: MFMA tile + row reductions ----------------
// Computes, per row i over this block's 128-col slice:
//   min over {an && d>hpos[i]} of d   -> atomicMin (bits, all vals >= 0)
//   max over {an} of d                -> atomicMax
//   flag bit0: any gbm, bit1: any negative -> atomicOr
template<bool COLCLASS>
__global__ __launch_bounds__(256) void k_pd(
    const unsigned short* __restrict__ rmat,   // [B][D] bf16 normalized
    const unsigned short* __restrict__ cmat,   // [N][D] bf16 normalized
    const float* __restrict__ rxx, const float* __restrict__ cxx,
    const int* __restrict__ rlab, const int* __restrict__ clab,
    const float* __restrict__ hpos,
    unsigned* __restrict__ mnv, unsigned* __restrict__ mxv,
    unsigned* __restrict__ flg, int D)
{
  const int j0 = blockIdx.x * 128, i0 = blockIdx.y * 128;
  __shared__ unsigned short lA[128 * 72];   // +8 pad: 2-way bank alias only (free)
  __shared__ unsigned short lB[128 * 72];
  const int tid = threadIdx.x;
  const int wid = tid >> 6, lane = tid & 63;
  const int wr = wid >> 1, wc = wid & 1;     // 2x2 waves, each 64x64 output
  const int lr = lane & 15, lg = lane >> 4;

  f32x4 zero = {0.f, 0.f, 0.f, 0.f};
  f32x4 acc[4][4];
  #pragma unroll
  for (int m = 0; m < 4; ++m)
    #pragma unroll
    for (int n = 0; n < 4; ++n) acc[m][n] = zero;

  for (int kt = 0; kt < D; kt += 64){
    #pragma unroll
    for (int it = 0; it < 4; ++it){
      int chunk = tid + it * 256;            // 1024 chunks of 8 bf16
      int r = chunk >> 3, c8 = (chunk & 7) * 8;
      *reinterpret_cast<short8*>(&lA[r * 72 + c8]) =
        *reinterpret_cast<const short8*>(&rmat[(size_t)(i0 + r) * D + kt + c8]);
      *reinterpret_cast<short8*>(&lB[r * 72 + c8]) =
        *reinterpret_cast<const short8*>(&cmat[(size_t)(j0 + r) * D + kt + c8]);
    }
    __syncthreads();
    #pragma unroll
    for (int ks = 0; ks < 64; ks += 32){
      short8 a[4], b[4];
      #pragma unroll
      for (int m = 0; m < 4; ++m)
        a[m] = *reinterpret_cast<const short8*>(&lA[(wr * 64 + m * 16 + lr) * 72 + ks + lg * 8]);
      #pragma unroll
      for (int n = 0; n < 4; ++n)
        b[n] = *reinterpret_cast<const short8*>(&lB[(wc * 64 + n * 16 + lr) * 72 + ks + lg * 8]);
      #pragma unroll
      for (int m = 0; m < 4; ++m)
        #pragma unroll
        for (int n = 0; n < 4; ++n)
          acc[m][n] = __builtin_amdgcn_mfma_f32_16x16x32_bf16(a[m], b[n], acc[m][n], 0, 0, 0);
    }
    __syncthreads();
  }

  // epilogue: distances + masked row reductions
  int jl[4]; float xj[4];
  #pragma unroll
  for (int n = 0; n < 4; ++n){
    int j = j0 + wc * 64 + n * 16 + lr;      // C/D frag: col = lane&15
    jl[n] = COLCLASS ? j : clab[j];
    xj[n] = cxx[j];
  }
  #pragma unroll
  for (int m = 0; m < 4; ++m){
    #pragma unroll
    for (int r = 0; r < 4; ++r){
      int i = i0 + wr * 64 + m * 16 + lg * 4 + r;  // C/D frag: row = (lane>>4)*4+reg
      int li = rlab[i];
      float xi = rxx[i];
      float hpi = hpos[i];
      float mn = BIGF, mx = 0.f; int fl = 0;
      #pragma unroll
      for (int n = 0; n < 4; ++n){
        float d2 = xi + xj[n] - 2.f * acc[m][n][r];
        float d  = sqrtf(fmaxf(d2, EPSC));
        bool an = (li != jl[n]);
        bool g  = an && (d > hpi);
        mn = fminf(mn, g ? d : BIGF);
        mx = fmaxf(mx, an ? d : 0.f);
        fl |= (g ? 1 : 0) | (an ? 2 : 0);
      }
      #pragma unroll
      for (int s = 1; s < 16; s <<= 1){      // reduce across the 16 j-lanes
        mn = fminf(mn, __shfl_xor(mn, s));
        mx = fmaxf(mx, __shfl_xor(mx, s));
        fl |= __shfl_xor(fl, s);
      }
      if (lr == 0){
        atomicMin(&mnv[i], __float_as_uint(mn));
        atomicMax(&mxv[i], __float_as_uint(mx));
        if (fl) atomicOr(&flg[i], (unsigned)fl);
      }
    }
  }
}

// ---------------- combine + loss ----------------
__global__ __launch_bounds__(256) void k_final(const float* __restrict__ hpos,
    const unsigned* __restrict__ mn0, const unsigned* __restrict__ mx0,
    const unsigned* __restrict__ fl0, const unsigned* __restrict__ mn1,
    const unsigned* __restrict__ mx1, const unsigned* __restrict__ fl1,
    const float* __restrict__ margin, float* __restrict__ out, int B){
  float part = 0.f;
  float mar = margin[0];
  for (int i = threadIdx.x; i < B; i += blockDim.x){
    float h_out = fminf(__uint_as_float(mn0[i]), __uint_as_float(mn1[i]));
    unsigned f0 = fl0[i], f1 = fl1[i];
    // neg_in = ms ? maxneg : (has_neg ? BIG : 0)
    float ni  = (!(f0 & 1u)) ? __uint_as_float(mx0[i]) : ((f0 & 2u) ? BIGF : 0.f);
    float nic = (!(f1 & 1u)) ? __uint_as_float(mx1[i]) : ((f1 & 2u) ? BIGF : 0.f);
    float h_in = fmaxf(ni, nic);
    float hneg = fminf(h_out, h_in);
    float t = hpos[i] - hneg + mar;
    part += fmaxf(t, 0.f);
  }
  float tot = block_reduce_sum(part);
  if (threadIdx.x == 0) out[0] = tot / (float)B;
}

extern "C" void kernel_launch(void* const* d_in, const int* in_sizes, int n_in,
                              void* d_out, int out_size, void* d_ws, size_t ws_size,
                              hipStream_t stream){
  const float* emb    = (const float*)d_in[0];
  const int*   labels = (const int*)d_in[1];
  const float* cval   = (const float*)d_in[2];
  const float* ccnt   = (const float*)d_in[3];
  const float* margin = (const float*)d_in[4];
  float* out = (float*)d_out;

  int B = in_sizes[1];
  int D = in_sizes[0] / B;
  int C = in_sizes[2] / D;
  const int MMAX = 64;

  char* ws = (char*)d_ws;
  size_t off = 0;
  auto alloc = [&](size_t bytes)->char*{
    char* p = ws + off;
    off = (off + bytes + 255) & ~(size_t)255;
    return p;
  };
  unsigned short* enb = (unsigned short*)alloc((size_t)B * D * 2);
  unsigned short* cnb = (unsigned short*)alloc((size_t)C * D * 2);
  float* exx  = (float*)alloc((size_t)B * 4);
  float* cxx  = (float*)alloc((size_t)C * 4);
  float* hpos = (float*)alloc((size_t)B * 4);
  unsigned* mn0 = (unsigned*)alloc((size_t)B * 4);
  unsigned* mx0 = (unsigned*)alloc((size_t)B * 4);
  unsigned* fl0 = (unsigned*)alloc((size_t)B * 4);
  unsigned* mn1 = (unsigned*)alloc((size_t)B * 4);
  unsigned* mx1 = (unsigned*)alloc((size_t)B * 4);
  unsigned* fl1 = (unsigned*)alloc((size_t)B * 4);
  int* cnt     = (int*)alloc((size_t)C * 4);
  int* members = (int*)alloc((size_t)C * MMAX * 4);
  (void)ws_size; (void)n_in; (void)out_size;   // ~21.3 MB used

  int mxBC = B > C ? B : C;
  k_init<<<(mxBC + 255) / 256, 256, 0, stream>>>(mn0, mx0, fl0, mn1, mx1, fl1, cnt, B, C);
  k_list<<<(B + 255) / 256, 256, (size_t)B * 4, stream>>>(labels, cnt, members, B, MMAX);
  k_norm_emb<<<B, 256, 0, stream>>>(emb, enb, exx, D);
  k_centers<<<C, 256, 0, stream>>>(emb, cval, ccnt, cnt, members, cnb, cxx, D, MMAX);
  k_hpos<<<B, 256, 0, stream>>>(enb, cnb, exx, cxx, labels, cnt, members, hpos, D, MMAX);
  dim3 g0(B / 128, B / 128);
  k_pd<false><<<g0, 256, 0, stream>>>(enb, enb, exx, exx, labels, labels, hpos,
                                      mn0, mx0, fl0, D);
  dim3 g1(C / 128, B / 128);
  k_pd<true><<<g1, 256, 0, stream>>>(enb, cnb, exx, cxx, labels, nullptr, hpos,
                                     mn1, mx1, fl1, D);
  k_final<<<1, 256, 0, stream>>>(hpos, mn0, mx0, fl0, mn1, mx1, fl1, margin, out, B);
}

// Round 2
// 281.030 us; speedup vs baseline: 1.1307x; 1.1307x over previous
//
#include <hip/hip_runtime.h>
#include <hip/hip_bf16.h>

// CaMLoss fused forward for MI355X (gfx950).
// B=4096, D=2048, C=1024 (derived from in_sizes). Assumes D%64==0, B,C%128==0.
// Fast paths assume D%512==0 (hpos) and D%2048==0 (norm/centers); generic
// fallbacks otherwise.

typedef __attribute__((ext_vector_type(8))) short short8;
typedef __attribute__((ext_vector_type(4))) float f32x4;

#define BIGF 1e6f
#define EPSC 1e-12f
#define MAXDD 16

__device__ __forceinline__ float bf2f(unsigned short u){
  unsigned int x = ((unsigned int)u) << 16;
  return __uint_as_float(x);
}
__device__ __forceinline__ unsigned short f2bf(float f){
  __hip_bfloat16 h = __float2bfloat16(f);
  return *reinterpret_cast<unsigned short*>(&h);
}

__device__ __forceinline__ float block_reduce_sum(float v){
  __shared__ float red[4];
  int tid = threadIdx.x;
  __syncthreads();
  #pragma unroll
  for (int s = 32; s; s >>= 1) v += __shfl_xor(v, s);
  if ((tid & 63) == 0) red[tid >> 6] = v;
  __syncthreads();
  return red[0] + red[1] + red[2] + red[3];
}

// async global->LDS, 16B per lane, wave-uniform LDS base + lane*16
#define GLL16(gptr, lptr) \
  __builtin_amdgcn_global_load_lds( \
      (const __attribute__((address_space(1))) unsigned int*)(gptr), \
      (__attribute__((address_space(3))) unsigned int*)(lptr), 16, 0, 0)

// ---------------- init per-row stats + class counters ----------------
__global__ void k_init(unsigned* mn0, unsigned* mx0, unsigned* fl0,
                       unsigned* mn1, unsigned* mx1, unsigned* fl1,
                       int* cnt, int B, int C){
  int i = blockIdx.x * blockDim.x + threadIdx.x;
  unsigned bigbits = __float_as_uint(BIGF);
  if (i < B){
    mn0[i] = bigbits; mx0[i] = 0u; fl0[i] = 0u;
    mn1[i] = bigbits; mx1[i] = 0u; fl1[i] = 0u;
  }
  if (i < C) cnt[i] = 0;
}

// ---------------- deterministic per-class member lists ----------------
__global__ void k_list(const int* __restrict__ labels, int* cnt,
                       int* members, int B, int MMAX){
  extern __shared__ int slab[];
  for (int j = threadIdx.x; j < B; j += blockDim.x) slab[j] = labels[j];
  __syncthreads();
  int i = blockIdx.x * blockDim.x + threadIdx.x;
  if (i >= B) return;
  int c = slab[i];
  atomicAdd(&cnt[c], 1);
  int rank = 0;
  int full = i & ~3;
  int j = 0;
  for (; j < full; j += 4){
    int4 l4 = *reinterpret_cast<const int4*>(&slab[j]);
    rank += (l4.x == c) + (l4.y == c) + (l4.z == c) + (l4.w == c);
  }
  for (; j < i; ++j) rank += (slab[j] == c) ? 1 : 0;
  if (rank < MMAX) members[c * MMAX + rank] = i;   // rank order => deterministic
}

// ---------------- normalize embeddings -> bf16 + xx (fast: D%2048==0) ----------------
template<int NCH>
__global__ __launch_bounds__(256) void k_norm_emb(const float* __restrict__ emb,
    unsigned short* __restrict__ enb, float* __restrict__ exx, int D){
  int i = blockIdx.x, tid = threadIdx.x;
  const float* row = emb + (size_t)i * D;
  float v[NCH][8];
  float ss = 0.f;
  #pragma unroll
  for (int ch = 0; ch < NCH; ++ch){
    int base = ch * 2048 + tid * 8;
    float4 a = *reinterpret_cast<const float4*>(&row[base]);
    float4 b = *reinterpret_cast<const float4*>(&row[base + 4]);
    v[ch][0]=a.x; v[ch][1]=a.y; v[ch][2]=a.z; v[ch][3]=a.w;
    v[ch][4]=b.x; v[ch][5]=b.y; v[ch][6]=b.z; v[ch][7]=b.w;
    #pragma unroll
    for (int k = 0; k < 8; ++k) ss += v[ch][k] * v[ch][k];
  }
  float tot = block_reduce_sum(ss);
  float inv = 1.f / (sqrtf(tot) + EPSC);
  unsigned short* orow = enb + (size_t)i * D;
  #pragma unroll
  for (int ch = 0; ch < NCH; ++ch){
    int base = ch * 2048 + tid * 8;
    short8 o;
    #pragma unroll
    for (int k = 0; k < 8; ++k) o[k] = (short)f2bf(v[ch][k] * inv);
    *reinterpret_cast<short8*>(&orow[base]) = o;
  }
  if (tid == 0) exx[i] = tot * inv * inv;
}

__global__ __launch_bounds__(256) void k_norm_emb_gen(const float* __restrict__ emb,
    unsigned short* __restrict__ enb, float* __restrict__ exx, int D){
  int i = blockIdx.x, tid = threadIdx.x;
  int DD = D >> 8;
  const float* row = emb + (size_t)i * D;
  float v[MAXDD];
  float ss = 0.f;
  for (int dd = 0; dd < DD; ++dd){ float x = row[dd * 256 + tid]; v[dd] = x; ss += x * x; }
  float tot = block_reduce_sum(ss);
  float inv = 1.f / (sqrtf(tot) + EPSC);
  unsigned short* orow = enb + (size_t)i * D;
  for (int dd = 0; dd < DD; ++dd) orow[dd * 256 + tid] = f2bf(v[dd] * inv);
  if (tid == 0) exx[i] = tot * inv * inv;
}

// ---------------- centers: update + normalize -> bf16 + xx ----------------
template<int NCH>
__global__ __launch_bounds__(256) void k_centers(const float* __restrict__ emb,
    const float* __restrict__ cval, const float* __restrict__ ccnt,
    const int* __restrict__ cnt, const int* __restrict__ members,
    unsigned short* __restrict__ cnb, float* __restrict__ cxx, int D, int MMAX){
  int c = blockIdx.x, tid = threadIdx.x;
  int n = cnt[c], m = n < MMAX ? n : MMAX;
  float acc[NCH][8];
  #pragma unroll
  for (int ch = 0; ch < NCH; ++ch)
    #pragma unroll
    for (int k = 0; k < 8; ++k) acc[ch][k] = 0.f;
  for (int e = 0; e < m; ++e){                       // ascending-index order
    const float* row = emb + (size_t)members[c * MMAX + e] * D;
    #pragma unroll
    for (int ch = 0; ch < NCH; ++ch){
      int base = ch * 2048 + tid * 8;
      float4 a = *reinterpret_cast<const float4*>(&row[base]);
      float4 b = *reinterpret_cast<const float4*>(&row[base + 4]);
      acc[ch][0]+=a.x; acc[ch][1]+=a.y; acc[ch][2]+=a.z; acc[ch][3]+=a.w;
      acc[ch][4]+=b.x; acc[ch][5]+=b.y; acc[ch][6]+=b.z; acc[ch][7]+=b.w;
    }
  }
  float cf = (float)n;
  float cen[NCH][8];
  float ss = 0.f;
  #pragma unroll
  for (int ch = 0; ch < NCH; ++ch){
    int base = ch * 2048 + tid * 8;
    float4 u0 = *reinterpret_cast<const float4*>(&ccnt[(size_t)c * D + base]);
    float4 u1 = *reinterpret_cast<const float4*>(&ccnt[(size_t)c * D + base + 4]);
    float4 w0 = *reinterpret_cast<const float4*>(&cval[(size_t)c * D + base]);
    float4 w1 = *reinterpret_cast<const float4*>(&cval[(size_t)c * D + base + 4]);
    float uc[8] = {u0.x,u0.y,u0.z,u0.w,u1.x,u1.y,u1.z,u1.w};
    float wv[8] = {w0.x,w0.y,w0.z,w0.w,w1.x,w1.y,w1.z,w1.w};
    #pragma unroll
    for (int k = 0; k < 8; ++k){
      float u = uc[k] + cf;
      float vv = wv[k] + acc[ch][k];
      float ce = (u > 0.f) ? (vv / fmaxf(u, 1.f)) : 0.f;
      cen[ch][k] = ce; ss += ce * ce;
    }
  }
  float tot = block_reduce_sum(ss);
  float inv = 1.f / (sqrtf(tot) + EPSC);
  #pragma unroll
  for (int ch = 0; ch < NCH; ++ch){
    int base = ch * 2048 + tid * 8;
    short8 o;
    #pragma unroll
    for (int k = 0; k < 8; ++k) o[k] = (short)f2bf(cen[ch][k] * inv);
    *reinterpret_cast<short8*>(&cnb[(size_t)c * D + base]) = o;
  }
  if (tid == 0) cxx[c] = tot * inv * inv;
}

__global__ __launch_bounds__(256) void k_centers_gen(const float* __restrict__ emb,
    const float* __restrict__ cval, const float* __restrict__ ccnt,
    const int* __restrict__ cnt, const int* __restrict__ members,
    unsigned short* __restrict__ cnb, float* __restrict__ cxx, int D, int MMAX){
  int c = blockIdx.x, tid = threadIdx.x;
  int DD = D >> 8;
  int n = cnt[c], m = n < MMAX ? n : MMAX;
  float acc[MAXDD];
  for (int dd = 0; dd < DD; ++dd) acc[dd] = 0.f;
  for (int e = 0; e < m; ++e){
    const float* row = emb + (size_t)members[c * MMAX + e] * D;
    for (int dd = 0; dd < DD; ++dd) acc[dd] += row[dd * 256 + tid];
  }
  float cf = (float)n;
  float cen[MAXDD];
  float ss = 0.f;
  for (int dd = 0; dd < DD; ++dd){
    int d = dd * 256 + tid;
    float uc = ccnt[(size_t)c * D + d] + cf;
    float vv = cval[(size_t)c * D + d] + acc[dd];
    float ce = (uc > 0.f) ? (vv / fmaxf(uc, 1.f)) : 0.f;
    cen[dd] = ce; ss += ce * ce;
  }
  float tot = block_reduce_sum(ss);
  float inv = 1.f / (sqrtf(tot) + EPSC);
  for (int dd = 0; dd < DD; ++dd)
    cnb[(size_t)c * D + dd * 256 + tid] = f2bf(cen[dd] * inv);
  if (tid == 0) cxx[c] = tot * inv * inv;
}

// ---------------- hardest positive: one wave per row (fast: D%512==0) ----------------
template<int NCH>
__global__ __launch_bounds__(256) void k_hpos(const unsigned short* __restrict__ enb,
    const unsigned short* __restrict__ cnb, const float* __restrict__ exx,
    const float* __restrict__ cxx, const int* __restrict__ labels,
    const int* __restrict__ cnt, const int* __restrict__ members,
    float* __restrict__ hpos, int D, int MMAX){
  int w = threadIdx.x >> 6, lane = threadIdx.x & 63;
  int i = blockIdx.x * 4 + w;
  int li = labels[i];
  const unsigned short* arow = enb + (size_t)i * D;
  float av[NCH][8];
  #pragma unroll
  for (int ch = 0; ch < NCH; ++ch){
    short8 a8 = *reinterpret_cast<const short8*>(&arow[ch * 512 + lane * 8]);
    #pragma unroll
    for (int k = 0; k < 8; ++k) av[ch][k] = bf2f((unsigned short)a8[k]);
  }
  float xi = exx[i];
  float hp = 0.f;
  int m = cnt[li] < MMAX ? cnt[li] : MMAX;
  for (int e = 0; e < m; ++e){
    int j = members[li * MMAX + e];
    if (j == i) continue;                     // wave-uniform
    const unsigned short* brow = enb + (size_t)j * D;
    float p = 0.f;
    #pragma unroll
    for (int ch = 0; ch < NCH; ++ch){
      short8 b8 = *reinterpret_cast<const short8*>(&brow[ch * 512 + lane * 8]);
      #pragma unroll
      for (int k = 0; k < 8; ++k) p += av[ch][k] * bf2f((unsigned short)b8[k]);
    }
    #pragma unroll
    for (int s = 1; s < 64; s <<= 1) p += __shfl_xor(p, s);
    float d2 = xi + exx[j] - 2.f * p;
    hp = fmaxf(hp, sqrtf(fmaxf(d2, EPSC)));
  }
  {
    const unsigned short* brow = cnb + (size_t)li * D;
    float p = 0.f;
    #pragma unroll
    for (int ch = 0; ch < NCH; ++ch){
      short8 b8 = *reinterpret_cast<const short8*>(&brow[ch * 512 + lane * 8]);
      #pragma unroll
      for (int k = 0; k < 8; ++k) p += av[ch][k] * bf2f((unsigned short)b8[k]);
    }
    #pragma unroll
    for (int s = 1; s < 64; s <<= 1) p += __shfl_xor(p, s);
    float d2 = xi + cxx[li] - 2.f * p;
    hp = fmaxf(hp, sqrtf(fmaxf(d2, EPSC)));
  }
  if (lane == 0) hpos[i] = hp;
}

// ---------------- fused distance pass: MFMA + row(/col) reductions ----------------
// global_load_lds staging (linear LDS, stride 64) + 128x128 tile, 4 waves.
// SYM: only tiles bx<=by run; off-diagonal tiles also emit column-side stats
// (mirrored ordered pairs, using hpos[j]); each ordered pair counted once.
template<bool COLCLASS, bool SYM>
__global__ __launch_bounds__(256) void k_pd(
    const unsigned short* __restrict__ rmat,   // [B][D] bf16 normalized
    const unsigned short* __restrict__ cmat,   // [N][D] bf16 normalized
    const float* __restrict__ rxx, const float* __restrict__ cxx,
    const int* __restrict__ rlab, const int* __restrict__ clab,
    const float* __restrict__ hpos,
    unsigned* __restrict__ mnv, unsigned* __restrict__ mxv,
    unsigned* __restrict__ flg, int D)
{
  const int bx = blockIdx.x, by = blockIdx.y;
  if (SYM && bx > by) return;
  const int j0 = bx * 128, i0 = by * 128;
  __shared__ unsigned short lA[128 * 64];
  __shared__ unsigned short lB[128 * 64];
  const int tid = threadIdx.x;
  const int wid = tid >> 6, lane = tid & 63;
  const int wr = wid >> 1, wc = wid & 1;     // 2x2 waves, each 64x64 output
  const int lr = lane & 15, lg = lane >> 4;

  // staging source: wave wid covers rows [wid*32, wid*32+32), 8 rows/call
  const int srow = wid * 32 + (lane >> 3);
  const int scol = (lane & 7) * 8;
  const unsigned short* gA = rmat + (size_t)(i0 + srow) * D + scol;
  const unsigned short* gB = cmat + (size_t)(j0 + srow) * D + scol;

  f32x4 zero = {0.f, 0.f, 0.f, 0.f};
  f32x4 acc[4][4];
  #pragma unroll
  for (int m = 0; m < 4; ++m)
    #pragma unroll
    for (int n = 0; n < 4; ++n) acc[m][n] = zero;

  for (int kt = 0; kt < D; kt += 64){
    #pragma unroll
    for (int it = 0; it < 4; ++it){
      GLL16(gA + kt + it * 8 * D, &lA[(wid * 32 + it * 8) * 64]);
      GLL16(gB + kt + it * 8 * D, &lB[(wid * 32 + it * 8) * 64]);
    }
    __syncthreads();
    #pragma unroll
    for (int ks = 0; ks < 64; ks += 32){
      short8 a[4], b[4];
      #pragma unroll
      for (int m = 0; m < 4; ++m)
        a[m] = *reinterpret_cast<const short8*>(&lA[(wr * 64 + m * 16 + lr) * 64 + ks + lg * 8]);
      #pragma unroll
      for (int n = 0; n < 4; ++n)
        b[n] = *reinterpret_cast<const short8*>(&lB[(wc * 64 + n * 16 + lr) * 64 + ks + lg * 8]);
      #pragma unroll
      for (int m = 0; m < 4; ++m)
        #pragma unroll
        for (int n = 0; n < 4; ++n)
          acc[m][n] = __builtin_amdgcn_mfma_f32_16x16x32_bf16(a[m], b[n], acc[m][n], 0, 0, 0);
    }
    __syncthreads();
  }

  // epilogue
  const bool docol = SYM && (bx != by);
  int jl[4]; float xj[4], hpj[4];
  #pragma unroll
  for (int n = 0; n < 4; ++n){
    int j = j0 + wc * 64 + n * 16 + lr;      // C/D frag: col = lane&15
    jl[n] = COLCLASS ? j : clab[j];
    xj[n] = cxx[j];
    hpj[n] = SYM ? hpos[j] : 0.f;
  }
  float cmn[4], cmx[4]; int cfl[4];
  #pragma unroll
  for (int n = 0; n < 4; ++n){ cmn[n] = BIGF; cmx[n] = 0.f; cfl[n] = 0; }

  #pragma unroll
  for (int m = 0; m < 4; ++m){
    #pragma unroll
    for (int r = 0; r < 4; ++r){
      int i = i0 + wr * 64 + m * 16 + lg * 4 + r;  // C/D frag: row=(lane>>4)*4+reg
      int li = rlab[i];
      float xi = rxx[i];
      float hpi = hpos[i];
      float mn = BIGF, mx = 0.f; int fl = 0;
      #pragma unroll
      for (int n = 0; n < 4; ++n){
        float d2 = xi + xj[n] - 2.f * acc[m][n][r];
        float d  = sqrtf(fmaxf(d2, EPSC));
        bool an = (li != jl[n]);
        bool g  = an && (d > hpi);
        mn = fminf(mn, g ? d : BIGF);
        mx = fmaxf(mx, an ? d : 0.f);
        fl |= (g ? 1 : 0) | (an ? 2 : 0);
        if (docol){
          bool gc = an && (d > hpj[n]);
          cmn[n] = fminf(cmn[n], gc ? d : BIGF);
          cmx[n] = fmaxf(cmx[n], an ? d : 0.f);
          cfl[n] |= (gc ? 1 : 0) | (an ? 2 : 0);
        }
      }
      #pragma unroll
      for (int s = 1; s < 16; s <<= 1){      // reduce across the 16 j-lanes
        mn = fminf(mn, __shfl_xor(mn, s));
        mx = fmaxf(mx, __shfl_xor(mx, s));
        fl |= __shfl_xor(fl, s);
      }
      if (lr == 0){
        atomicMin(&mnv[i], __float_as_uint(mn));
        atomicMax(&mxv[i], __float_as_uint(mx));
        if (fl) atomicOr(&flg[i], (unsigned)fl);
      }
    }
  }
  if (docol){
    #pragma unroll
    for (int n = 0; n < 4; ++n){
      float mn = cmn[n], mx = cmx[n]; int fl = cfl[n];
      #pragma unroll
      for (int s = 16; s < 64; s <<= 1){     // reduce across the 4 lg groups
        mn = fminf(mn, __shfl_xor(mn, s));
        mx = fmaxf(mx, __shfl_xor(mx, s));
        fl |= __shfl_xor(fl, s);
      }
      if (lg == 0){
        int j = j0 + wc * 64 + n * 16 + lr;
        atomicMin(&mnv[j], __float_as_uint(mn));
        atomicMax(&mxv[j], __float_as_uint(mx));
        if (fl) atomicOr(&flg[j], (unsigned)fl);
      }
    }
  }
}

// ---------------- combine + loss ----------------
__global__ __launch_bounds__(256) void k_final(const float* __restrict__ hpos,
    const unsigned* __restrict__ mn0, const unsigned* __restrict__ mx0,
    const unsigned* __restrict__ fl0, const unsigned* __restrict__ mn1,
    const unsigned* __restrict__ mx1, const unsigned* __restrict__ fl1,
    const float* __restrict__ margin, float* __restrict__ out, int B){
  float part = 0.f;
  float mar = margin[0];
  for (int i = threadIdx.x; i < B; i += blockDim.x){
    float h_out = fminf(__uint_as_float(mn0[i]), __uint_as_float(mn1[i]));
    unsigned f0 = fl0[i], f1 = fl1[i];
    float ni  = (!(f0 & 1u)) ? __uint_as_float(mx0[i]) : ((f0 & 2u) ? BIGF : 0.f);
    float nic = (!(f1 & 1u)) ? __uint_as_float(mx1[i]) : ((f1 & 2u) ? BIGF : 0.f);
    float h_in = fmaxf(ni, nic);
    float hneg = fminf(h_out, h_in);
    float t = hpos[i] - hneg + mar;
    part += fmaxf(t, 0.f);
  }
  float tot = block_reduce_sum(part);
  if (threadIdx.x == 0) out[0] = tot / (float)B;
}

extern "C" void kernel_launch(void* const* d_in, const int* in_sizes, int n_in,
                              void* d_out, int out_size, void* d_ws, size_t ws_size,
                              hipStream_t stream){
  const float* emb    = (const float*)d_in[0];
  const int*   labels = (const int*)d_in[1];
  const float* cval   = (const float*)d_in[2];
  const float* ccnt   = (const float*)d_in[3];
  const float* margin = (const float*)d_in[4];
  float* out = (float*)d_out;

  int B = in_sizes[1];
  int D = in_sizes[0] / B;
  int C = in_sizes[2] / D;
  const int MMAX = 64;

  char* ws = (char*)d_ws;
  size_t off = 0;
  auto alloc = [&](size_t bytes)->char*{
    char* p = ws + off;
    off = (off + bytes + 255) & ~(size_t)255;
    return p;
  };
  unsigned short* enb = (unsigned short*)alloc((size_t)B * D * 2);
  unsigned short* cnb = (unsigned short*)alloc((size_t)C * D * 2);
  float* exx  = (float*)alloc((size_t)B * 4);
  float* cxx  = (float*)alloc((size_t)C * 4);
  float* hpos = (float*)alloc((size_t)B * 4);
  unsigned* mn0 = (unsigned*)alloc((size_t)B * 4);
  unsigned* mx0 = (unsigned*)alloc((size_t)B * 4);
  unsigned* fl0 = (unsigned*)alloc((size_t)B * 4);
  unsigned* mn1 = (unsigned*)alloc((size_t)B * 4);
  unsigned* mx1 = (unsigned*)alloc((size_t)B * 4);
  unsigned* fl1 = (unsigned*)alloc((size_t)B * 4);
  int* cnt     = (int*)alloc((size_t)C * 4);
  int* members = (int*)alloc((size_t)C * MMAX * 4);
  (void)ws_size; (void)n_in; (void)out_size;

  int mxBC = B > C ? B : C;
  k_init<<<(mxBC + 255) / 256, 256, 0, stream>>>(mn0, mx0, fl0, mn1, mx1, fl1, cnt, B, C);
  k_list<<<(B + 255) / 256, 256, (size_t)B * 4, stream>>>(labels, cnt, members, B, MMAX);

  if ((D & 2047) == 0 && (D >> 11) <= 2){
    if ((D >> 11) == 1){
      k_norm_emb<1><<<B, 256, 0, stream>>>(emb, enb, exx, D);
      k_centers<1><<<C, 256, 0, stream>>>(emb, cval, ccnt, cnt, members, cnb, cxx, D, MMAX);
    } else {
      k_norm_emb<2><<<B, 256, 0, stream>>>(emb, enb, exx, D);
      k_centers<2><<<C, 256, 0, stream>>>(emb, cval, ccnt, cnt, members, cnb, cxx, D, MMAX);
    }
  } else {
    k_norm_emb_gen<<<B, 256, 0, stream>>>(emb, enb, exx, D);
    k_centers_gen<<<C, 256, 0, stream>>>(emb, cval, ccnt, cnt, members, cnb, cxx, D, MMAX);
  }

  switch (D >> 9){   // D%512==0 fast paths; D=2048 -> 4
    case 1: k_hpos<1><<<B/4, 256, 0, stream>>>(enb, cnb, exx, cxx, labels, cnt, members, hpos, D, MMAX); break;
    case 2: k_hpos<2><<<B/4, 256, 0, stream>>>(enb, cnb, exx, cxx, labels, cnt, members, hpos, D, MMAX); break;
    case 3: k_hpos<3><<<B/4, 256, 0, stream>>>(enb, cnb, exx, cxx, labels, cnt, members, hpos, D, MMAX); break;
    case 4: k_hpos<4><<<B/4, 256, 0, stream>>>(enb, cnb, exx, cxx, labels, cnt, members, hpos, D, MMAX); break;
    case 6: k_hpos<6><<<B/4, 256, 0, stream>>>(enb, cnb, exx, cxx, labels, cnt, members, hpos, D, MMAX); break;
    case 8: k_hpos<8><<<B/4, 256, 0, stream>>>(enb, cnb, exx, cxx, labels, cnt, members, hpos, D, MMAX); break;
    default: k_hpos<1><<<B/4, 256, 0, stream>>>(enb, cnb, exx, cxx, labels, cnt, members, hpos, 512, MMAX); break;
  }

  dim3 g0(B / 128, B / 128);
  k_pd<false, true><<<g0, 256, 0, stream>>>(enb, enb, exx, exx, labels, labels, hpos,
                                            mn0, mx0, fl0, D);
  dim3 g1(C / 128, B / 128);
  k_pd<true, false><<<g1, 256, 0, stream>>>(enb, cnb, exx, cxx, labels, nullptr, hpos,
                                            mn1, mx1, fl1, D);
  k_final<<<1, 256, 0, stream>>>(hpos, mn0, mx0, fl0, mn1, mx1, fl1, margin, out, B);
}

// Round 3
// 192.136 us; speedup vs baseline: 1.6538x; 1.4627x over previous
//
#include <hip/hip_runtime.h>
#include <hip/hip_bf16.h>

// CaMLoss fused forward for MI355X (gfx950).
// B=4096, D=2048, C=1024 (derived from in_sizes). Assumes D%64==0, B,C%128==0.
// enb/cnb are stored SLOT-SWIZZLED: within each 64-elem chunk of row i, the
// 8-elem slot s of the original row is stored at slot s ^ (i&7). This makes the
// linear global_load_lds staging land swizzled in LDS so ds_read_b128 at
// idx ^ ((row&7)<<3) is bank-conflict-free (T2 via pre-swizzled source, m173).

typedef __attribute__((ext_vector_type(8))) short short8;
typedef __attribute__((ext_vector_type(4))) float f32x4;

#define BIGF 1e6f
#define EPSC 1e-12f
#define MAXDD 16

__device__ __forceinline__ float bf2f(unsigned short u){
  unsigned int x = ((unsigned int)u) << 16;
  return __uint_as_float(x);
}
__device__ __forceinline__ unsigned short f2bf(float f){
  __hip_bfloat16 h = __float2bfloat16(f);
  return *reinterpret_cast<unsigned short*>(&h);
}

__device__ __forceinline__ float block_reduce_sum(float v){
  __shared__ float red[4];
  int tid = threadIdx.x;
  __syncthreads();
  #pragma unroll
  for (int s = 32; s; s >>= 1) v += __shfl_xor(v, s);
  if ((tid & 63) == 0) red[tid >> 6] = v;
  __syncthreads();
  return red[0] + red[1] + red[2] + red[3];
}

// async global->LDS, 16B per lane, wave-uniform LDS base + lane*16
#define GLL16(gptr, lptr) \
  __builtin_amdgcn_global_load_lds( \
      (const __attribute__((address_space(1))) unsigned int*)(gptr), \
      (__attribute__((address_space(3))) unsigned int*)(lptr), 16, 0, 0)

// ---------------- init per-row stats + class counters ----------------
__global__ void k_init(unsigned* mn0, unsigned* mx0, unsigned* fl0,
                       unsigned* mn1, unsigned* mx1, unsigned* fl1,
                       int* cnt, int B, int C){
  int i = blockIdx.x * blockDim.x + threadIdx.x;
  unsigned bigbits = __float_as_uint(BIGF);
  if (i < B){
    mn0[i] = bigbits; mx0[i] = 0u; fl0[i] = 0u;
    mn1[i] = bigbits; mx1[i] = 0u; fl1[i] = 0u;
  }
  if (i < C) cnt[i] = 0;
}

// ---------------- deterministic per-class member lists ----------------
__global__ void k_list(const int* __restrict__ labels, int* cnt,
                       int* members, int B, int MMAX){
  extern __shared__ int slab[];
  for (int j = threadIdx.x; j < B; j += blockDim.x) slab[j] = labels[j];
  __syncthreads();
  int i = blockIdx.x * blockDim.x + threadIdx.x;
  if (i >= B) return;
  int c = slab[i];
  atomicAdd(&cnt[c], 1);
  int rank = 0;
  int full = i & ~3;
  int j = 0;
  for (; j < full; j += 4){
    int4 l4 = *reinterpret_cast<const int4*>(&slab[j]);
    rank += (l4.x == c) + (l4.y == c) + (l4.z == c) + (l4.w == c);
  }
  for (; j < i; ++j) rank += (slab[j] == c) ? 1 : 0;
  if (rank < MMAX) members[c * MMAX + rank] = i;   // rank order => deterministic
}

// ---------------- normalize embeddings -> swizzled bf16 + xx ----------------
template<int NCH>
__global__ __launch_bounds__(256) void k_norm_emb(const float* __restrict__ emb,
    unsigned short* __restrict__ enb, float* __restrict__ exx, int D){
  int i = blockIdx.x, tid = threadIdx.x;
  const float* row = emb + (size_t)i * D;
  float v[NCH][8];
  float ss = 0.f;
  #pragma unroll
  for (int ch = 0; ch < NCH; ++ch){
    int base = ch * 2048 + tid * 8;
    float4 a = *reinterpret_cast<const float4*>(&row[base]);
    float4 b = *reinterpret_cast<const float4*>(&row[base + 4]);
    v[ch][0]=a.x; v[ch][1]=a.y; v[ch][2]=a.z; v[ch][3]=a.w;
    v[ch][4]=b.x; v[ch][5]=b.y; v[ch][6]=b.z; v[ch][7]=b.w;
    #pragma unroll
    for (int k = 0; k < 8; ++k) ss += v[ch][k] * v[ch][k];
  }
  float tot = block_reduce_sum(ss);
  float inv = 1.f / (sqrtf(tot) + EPSC);
  unsigned short* orow = enb + (size_t)i * D;
  int xr = (i & 7) << 3;
  #pragma unroll
  for (int ch = 0; ch < NCH; ++ch){
    int base = (ch * 2048 + tid * 8) ^ xr;     // swizzled slot
    short8 o;
    #pragma unroll
    for (int k = 0; k < 8; ++k) o[k] = (short)f2bf(v[ch][k] * inv);
    *reinterpret_cast<short8*>(&orow[base]) = o;
  }
  if (tid == 0) exx[i] = tot * inv * inv;
}

__global__ __launch_bounds__(256) void k_norm_emb_gen(const float* __restrict__ emb,
    unsigned short* __restrict__ enb, float* __restrict__ exx, int D){
  int i = blockIdx.x, tid = threadIdx.x;
  int DD = D >> 8;
  const float* row = emb + (size_t)i * D;
  float v[MAXDD];
  float ss = 0.f;
  for (int dd = 0; dd < DD; ++dd){ float x = row[dd * 256 + tid]; v[dd] = x; ss += x * x; }
  float tot = block_reduce_sum(ss);
  float inv = 1.f / (sqrtf(tot) + EPSC);
  unsigned short* orow = enb + (size_t)i * D;
  int xr = (i & 7) << 3;
  for (int dd = 0; dd < DD; ++dd) orow[(dd * 256 + tid) ^ xr] = f2bf(v[dd] * inv);
  if (tid == 0) exx[i] = tot * inv * inv;
}

// ---------------- centers: update + normalize -> swizzled bf16 + xx ----------------
template<int NCH>
__global__ __launch_bounds__(256) void k_centers(const float* __restrict__ emb,
    const float* __restrict__ cval, const float* __restrict__ ccnt,
    const int* __restrict__ cnt, const int* __restrict__ members,
    unsigned short* __restrict__ cnb, float* __restrict__ cxx, int D, int MMAX){
  int c = blockIdx.x, tid = threadIdx.x;
  int n = cnt[c], m = n < MMAX ? n : MMAX;
  float acc[NCH][8];
  #pragma unroll
  for (int ch = 0; ch < NCH; ++ch)
    #pragma unroll
    for (int k = 0; k < 8; ++k) acc[ch][k] = 0.f;
  for (int e = 0; e < m; ++e){                       // ascending-index order
    const float* row = emb + (size_t)members[c * MMAX + e] * D;
    #pragma unroll
    for (int ch = 0; ch < NCH; ++ch){
      int base = ch * 2048 + tid * 8;
      float4 a = *reinterpret_cast<const float4*>(&row[base]);
      float4 b = *reinterpret_cast<const float4*>(&row[base + 4]);
      acc[ch][0]+=a.x; acc[ch][1]+=a.y; acc[ch][2]+=a.z; acc[ch][3]+=a.w;
      acc[ch][4]+=b.x; acc[ch][5]+=b.y; acc[ch][6]+=b.z; acc[ch][7]+=b.w;
    }
  }
  float cf = (float)n;
  float cen[NCH][8];
  float ss = 0.f;
  #pragma unroll
  for (int ch = 0; ch < NCH; ++ch){
    int base = ch * 2048 + tid * 8;
    float4 u0 = *reinterpret_cast<const float4*>(&ccnt[(size_t)c * D + base]);
    float4 u1 = *reinterpret_cast<const float4*>(&ccnt[(size_t)c * D + base + 4]);
    float4 w0 = *reinterpret_cast<const float4*>(&cval[(size_t)c * D + base]);
    float4 w1 = *reinterpret_cast<const float4*>(&cval[(size_t)c * D + base + 4]);
    float uc[8] = {u0.x,u0.y,u0.z,u0.w,u1.x,u1.y,u1.z,u1.w};
    float wv[8] = {w0.x,w0.y,w0.z,w0.w,w1.x,w1.y,w1.z,w1.w};
    #pragma unroll
    for (int k = 0; k < 8; ++k){
      float u = uc[k] + cf;
      float vv = wv[k] + acc[ch][k];
      float ce = (u > 0.f) ? (vv / fmaxf(u, 1.f)) : 0.f;
      cen[ch][k] = ce; ss += ce * ce;
    }
  }
  float tot = block_reduce_sum(ss);
  float inv = 1.f / (sqrtf(tot) + EPSC);
  int xr = (c & 7) << 3;
  #pragma unroll
  for (int ch = 0; ch < NCH; ++ch){
    int base = (ch * 2048 + tid * 8) ^ xr;     // swizzled slot
    short8 o;
    #pragma unroll
    for (int k = 0; k < 8; ++k) o[k] = (short)f2bf(cen[ch][k] * inv);
    *reinterpret_cast<short8*>(&cnb[(size_t)c * D + base]) = o;
  }
  if (tid == 0) cxx[c] = tot * inv * inv;
}

__global__ __launch_bounds__(256) void k_centers_gen(const float* __restrict__ emb,
    const float* __restrict__ cval, const float* __restrict__ ccnt,
    const int* __restrict__ cnt, const int* __restrict__ members,
    unsigned short* __restrict__ cnb, float* __restrict__ cxx, int D, int MMAX){
  int c = blockIdx.x, tid = threadIdx.x;
  int DD = D >> 8;
  int n = cnt[c], m = n < MMAX ? n : MMAX;
  float acc[MAXDD];
  for (int dd = 0; dd < DD; ++dd) acc[dd] = 0.f;
  for (int e = 0; e < m; ++e){
    const float* row = emb + (size_t)members[c * MMAX + e] * D;
    for (int dd = 0; dd < DD; ++dd) acc[dd] += row[dd * 256 + tid];
  }
  float cf = (float)n;
  float cen[MAXDD];
  float ss = 0.f;
  for (int dd = 0; dd < DD; ++dd){
    int d = dd * 256 + tid;
    float uc = ccnt[(size_t)c * D + d] + cf;
    float vv = cval[(size_t)c * D + d] + acc[dd];
    float ce = (uc > 0.f) ? (vv / fmaxf(uc, 1.f)) : 0.f;
    cen[dd] = ce; ss += ce * ce;
  }
  float tot = block_reduce_sum(ss);
  float inv = 1.f / (sqrtf(tot) + EPSC);
  int xr = (c & 7) << 3;
  for (int dd = 0; dd < DD; ++dd)
    cnb[(size_t)c * D + ((dd * 256 + tid) ^ xr)] = f2bf(cen[dd] * inv);
  if (tid == 0) cxx[c] = tot * inv * inv;
}

// ---------------- hardest positive: one wave per row ----------------
// Reads the swizzled layout: per-row XOR (row&7)<<3 on the element index.
template<int NCH>
__global__ __launch_bounds__(256) void k_hpos(const unsigned short* __restrict__ enb,
    const unsigned short* __restrict__ cnb, const float* __restrict__ exx,
    const float* __restrict__ cxx, const int* __restrict__ labels,
    const int* __restrict__ cnt, const int* __restrict__ members,
    float* __restrict__ hpos, int D, int MMAX){
  int w = threadIdx.x >> 6, lane = threadIdx.x & 63;
  int i = blockIdx.x * 4 + w;
  int li = labels[i];
  const unsigned short* arow = enb + (size_t)i * D;
  int xri = (i & 7) << 3;
  float av[NCH][8];
  #pragma unroll
  for (int ch = 0; ch < NCH; ++ch){
    short8 a8 = *reinterpret_cast<const short8*>(&arow[(ch * 512 + lane * 8) ^ xri]);
    #pragma unroll
    for (int k = 0; k < 8; ++k) av[ch][k] = bf2f((unsigned short)a8[k]);
  }
  float xi = exx[i];
  float hp = 0.f;
  int m = cnt[li] < MMAX ? cnt[li] : MMAX;
  for (int e = 0; e < m; ++e){
    int j = members[li * MMAX + e];
    if (j == i) continue;                     // wave-uniform
    const unsigned short* brow = enb + (size_t)j * D;
    int xrj = (j & 7) << 3;
    float p = 0.f;
    #pragma unroll
    for (int ch = 0; ch < NCH; ++ch){
      short8 b8 = *reinterpret_cast<const short8*>(&brow[(ch * 512 + lane * 8) ^ xrj]);
      #pragma unroll
      for (int k = 0; k < 8; ++k) p += av[ch][k] * bf2f((unsigned short)b8[k]);
    }
    #pragma unroll
    for (int s = 1; s < 64; s <<= 1) p += __shfl_xor(p, s);
    float d2 = xi + exx[j] - 2.f * p;
    hp = fmaxf(hp, sqrtf(fmaxf(d2, EPSC)));
  }
  {
    const unsigned short* brow = cnb + (size_t)li * D;
    int xrc = (li & 7) << 3;
    float p = 0.f;
    #pragma unroll
    for (int ch = 0; ch < NCH; ++ch){
      short8 b8 = *reinterpret_cast<const short8*>(&brow[(ch * 512 + lane * 8) ^ xrc]);
      #pragma unroll
      for (int k = 0; k < 8; ++k) p += av[ch][k] * bf2f((unsigned short)b8[k]);
    }
    #pragma unroll
    for (int s = 1; s < 64; s <<= 1) p += __shfl_xor(p, s);
    float d2 = xi + cxx[li] - 2.f * p;
    hp = fmaxf(hp, sqrtf(fmaxf(d2, EPSC)));
  }
  if (lane == 0) hpos[i] = hp;
}

// generic (D % 512 == 0): re-reads A per member, runtime chunk loop
__global__ __launch_bounds__(256) void k_hpos_gen(const unsigned short* __restrict__ enb,
    const unsigned short* __restrict__ cnb, const float* __restrict__ exx,
    const float* __restrict__ cxx, const int* __restrict__ labels,
    const int* __restrict__ cnt, const int* __restrict__ members,
    float* __restrict__ hpos, int D, int MMAX){
  int w = threadIdx.x >> 6, lane = threadIdx.x & 63;
  int i = blockIdx.x * 4 + w;
  int li = labels[i];
  const unsigned short* arow = enb + (size_t)i * D;
  int xri = (i & 7) << 3;
  float xi = exx[i];
  int nch = D >> 9;
  float hp = 0.f;
  int m = cnt[li] < MMAX ? cnt[li] : MMAX;
  for (int e = 0; e <= m; ++e){
    int j; const unsigned short* brow; float xjv; int xrj;
    if (e < m){
      j = members[li * MMAX + e];
      if (j == i) continue;
      brow = enb + (size_t)j * D; xjv = exx[j]; xrj = (j & 7) << 3;
    } else {
      brow = cnb + (size_t)li * D; xjv = cxx[li]; xrj = (li & 7) << 3;
    }
    float p = 0.f;
    for (int ch = 0; ch < nch; ++ch){
      short8 a8 = *reinterpret_cast<const short8*>(&arow[(ch * 512 + lane * 8) ^ xri]);
      short8 b8 = *reinterpret_cast<const short8*>(&brow[(ch * 512 + lane * 8) ^ xrj]);
      #pragma unroll
      for (int k = 0; k < 8; ++k)
        p += bf2f((unsigned short)a8[k]) * bf2f((unsigned short)b8[k]);
    }
    #pragma unroll
    for (int s = 1; s < 64; s <<= 1) p += __shfl_xor(p, s);
    float d2 = xi + xjv - 2.f * p;
    hp = fmaxf(hp, sqrtf(fmaxf(d2, EPSC)));
  }
  if (lane == 0) hpos[i] = hp;
}

// ---------------- merged distance pass: tri(pd) + pdc tiles in one grid ----------------
// min-2-phase: double-buffered LDS, next tile's global_load_lds issued before
// current tile's compute; one barrier per K-step. ds_read swizzled by
// idx ^ ((row&7)<<3) against the pre-swizzled global layout -> ~2-way conflicts.
__global__ __launch_bounds__(256) void k_pd_all(
    const unsigned short* __restrict__ enb,
    const unsigned short* __restrict__ cnb,
    const float* __restrict__ exx, const float* __restrict__ cxx,
    const int* __restrict__ labels, const float* __restrict__ hpos,
    unsigned* __restrict__ mn0, unsigned* __restrict__ mx0, unsigned* __restrict__ fl0,
    unsigned* __restrict__ mn1, unsigned* __restrict__ mx1, unsigned* __restrict__ fl1,
    int D, int nTri, int nCx)
{
  __shared__ unsigned short lds[2][2][128 * 64];   // [buf][A/B][row][64] = 64 KiB
  const int t = blockIdx.x;
  const bool pdc = (t >= nTri);
  int bx, by;
  if (!pdc){
    int b = (int)((sqrtf(8.f * (float)t + 1.f) - 1.f) * 0.5f);
    while ((b + 1) * (b + 2) / 2 <= t) ++b;
    while (b * (b + 1) / 2 > t) --b;
    by = b; bx = t - b * (b + 1) / 2;              // bx <= by
  } else {
    int u = t - nTri;
    by = u / nCx; bx = u - by * nCx;
  }
  const unsigned short* cmat = pdc ? cnb : enb;
  const float* cxv = pdc ? cxx : exx;
  unsigned* mnv = pdc ? mn1 : mn0;
  unsigned* mxv = pdc ? mx1 : mx0;
  unsigned* flv = pdc ? fl1 : fl0;

  const int j0 = bx * 128, i0 = by * 128;
  const int tid = threadIdx.x;
  const int wid = tid >> 6, lane = tid & 63;
  const int wr = wid >> 1, wc = wid & 1;           // 2x2 waves, each 64x64 out
  const int lr = lane & 15, lg = lane >> 4;
  const int xr3 = (lr & 7) << 3;

  // staging: wave wid covers tile rows [wid*32, wid*32+32), 8 rows per GLL16
  const int srow = wid * 32 + (lane >> 3);
  const int scol = (lane & 7) * 8;
  const unsigned short* gA = enb  + (size_t)(i0 + srow) * D + scol;
  const unsigned short* gB = cmat + (size_t)(j0 + srow) * D + scol;

  f32x4 zero = {0.f, 0.f, 0.f, 0.f};
  f32x4 acc[4][4];
  #pragma unroll
  for (int m = 0; m < 4; ++m)
    #pragma unroll
    for (int n = 0; n < 4; ++n) acc[m][n] = zero;

  auto STAGE = [&](int kt, int cur){
    #pragma unroll
    for (int it2 = 0; it2 < 4; ++it2){
      GLL16(gA + (size_t)kt + (size_t)it2 * 8 * D, &lds[cur][0][(wid * 32 + it2 * 8) * 64]);
      GLL16(gB + (size_t)kt + (size_t)it2 * 8 * D, &lds[cur][1][(wid * 32 + it2 * 8) * 64]);
    }
  };

  STAGE(0, 0);
  __syncthreads();                                  // drains vmcnt
  const int nt = D >> 6;
  for (int it = 0; it < nt; ++it){
    int cur = it & 1;
    if (it + 1 < nt) STAGE((it + 1) << 6, cur ^ 1); // prefetch overlaps compute
    const unsigned short* lA = lds[cur][0];
    const unsigned short* lB = lds[cur][1];
    #pragma unroll
    for (int ks = 0; ks < 64; ks += 32){
      short8 a[4], b[4];
      #pragma unroll
      for (int m = 0; m < 4; ++m)
        a[m] = *reinterpret_cast<const short8*>(
            &lA[((wr * 64 + m * 16 + lr) * 64 + ks + lg * 8) ^ xr3]);
      #pragma unroll
      for (int n = 0; n < 4; ++n)
        b[n] = *reinterpret_cast<const short8*>(
            &lB[((wc * 64 + n * 16 + lr) * 64 + ks + lg * 8) ^ xr3]);
      #pragma unroll
      for (int m = 0; m < 4; ++m)
        #pragma unroll
        for (int n = 0; n < 4; ++n)
          acc[m][n] = __builtin_amdgcn_mfma_f32_16x16x32_bf16(a[m], b[n], acc[m][n], 0, 0, 0);
    }
    __syncthreads();                                // next buffer staged + all reads done
  }

  // epilogue
  const bool docol = (!pdc) && (bx != by);
  int jl[4]; float xj[4], hpj[4];
  #pragma unroll
  for (int n = 0; n < 4; ++n){
    int j = j0 + wc * 64 + n * 16 + lr;             // C/D frag: col = lane&15
    jl[n] = pdc ? j : labels[j];
    xj[n] = cxv[j];
    hpj[n] = docol ? hpos[j] : 0.f;
  }
  float cmn[4], cmx[4]; int cfl[4];
  #pragma unroll
  for (int n = 0; n < 4; ++n){ cmn[n] = BIGF; cmx[n] = 0.f; cfl[n] = 0; }

  #pragma unroll
  for (int m = 0; m < 4; ++m){
    #pragma unroll
    for (int r = 0; r < 4; ++r){
      int i = i0 + wr * 64 + m * 16 + lg * 4 + r;   // C/D frag: row=(lane>>4)*4+reg
      int li = labels[i];
      float xi = exx[i];
      float hpi = hpos[i];
      float mn = BIGF, mx = 0.f; int fl = 0;
      #pragma unroll
      for (int n = 0; n < 4; ++n){
        float d2 = xi + xj[n] - 2.f * acc[m][n][r];
        float d  = sqrtf(fmaxf(d2, EPSC));
        bool an = (li != jl[n]);
        bool g  = an && (d > hpi);
        mn = fminf(mn, g ? d : BIGF);
        mx = fmaxf(mx, an ? d : 0.f);
        fl |= (g ? 1 : 0) | (an ? 2 : 0);
        if (docol){
          bool gc = an && (d > hpj[n]);
          cmn[n] = fminf(cmn[n], gc ? d : BIGF);
          cmx[n] = fmaxf(cmx[n], an ? d : 0.f);
          cfl[n] |= (gc ? 1 : 0) | (an ? 2 : 0);
        }
      }
      #pragma unroll
      for (int s = 1; s < 16; s <<= 1){             // reduce across 16 j-lanes
        mn = fminf(mn, __shfl_xor(mn, s));
        mx = fmaxf(mx, __shfl_xor(mx, s));
        fl |= __shfl_xor(fl, s);
      }
      if (lr == 0){
        atomicMin(&mnv[i], __float_as_uint(mn));
        atomicMax(&mxv[i], __float_as_uint(mx));
        if (fl) atomicOr(&flv[i], (unsigned)fl);
      }
    }
  }
  if (docol){
    #pragma unroll
    for (int n = 0; n < 4; ++n){
      float mn = cmn[n], mx = cmx[n]; int fl = cfl[n];
      #pragma unroll
      for (int s = 16; s < 64; s <<= 1){            // reduce across 4 lg groups
        mn = fminf(mn, __shfl_xor(mn, s));
        mx = fmaxf(mx, __shfl_xor(mx, s));
        fl |= __shfl_xor(fl, s);
      }
      if (lg == 0){
        int j = j0 + wc * 64 + n * 16 + lr;
        atomicMin(&mn0[j], __float_as_uint(mn));
        atomicMax(&mx0[j], __float_as_uint(mx));
        if (fl) atomicOr(&fl0[j], (unsigned)fl);
      }
    }
  }
}

// ---------------- combine + loss ----------------
__global__ __launch_bounds__(256) void k_final(const float* __restrict__ hpos,
    const unsigned* __restrict__ mn0, const unsigned* __restrict__ mx0,
    const unsigned* __restrict__ fl0, const unsigned* __restrict__ mn1,
    const unsigned* __restrict__ mx1, const unsigned* __restrict__ fl1,
    const float* __restrict__ margin, float* __restrict__ out, int B){
  float part = 0.f;
  float mar = margin[0];
  for (int i = threadIdx.x; i < B; i += blockDim.x){
    float h_out = fminf(__uint_as_float(mn0[i]), __uint_as_float(mn1[i]));
    unsigned f0 = fl0[i], f1 = fl1[i];
    float ni  = (!(f0 & 1u)) ? __uint_as_float(mx0[i]) : ((f0 & 2u) ? BIGF : 0.f);
    float nic = (!(f1 & 1u)) ? __uint_as_float(mx1[i]) : ((f1 & 2u) ? BIGF : 0.f);
    float h_in = fmaxf(ni, nic);
    float hneg = fminf(h_out, h_in);
    float t = hpos[i] - hneg + mar;
    part += fmaxf(t, 0.f);
  }
  float tot = block_reduce_sum(part);
  if (threadIdx.x == 0) out[0] = tot / (float)B;
}

extern "C" void kernel_launch(void* const* d_in, const int* in_sizes, int n_in,
                              void* d_out, int out_size, void* d_ws, size_t ws_size,
                              hipStream_t stream){
  const float* emb    = (const float*)d_in[0];
  const int*   labels = (const int*)d_in[1];
  const float* cval   = (const float*)d_in[2];
  const float* ccnt   = (const float*)d_in[3];
  const float* margin = (const float*)d_in[4];
  float* out = (float*)d_out;

  int B = in_sizes[1];
  int D = in_sizes[0] / B;
  int C = in_sizes[2] / D;
  const int MMAX = 64;

  char* ws = (char*)d_ws;
  size_t off = 0;
  auto alloc = [&](size_t bytes)->char*{
    char* p = ws + off;
    off = (off + bytes + 255) & ~(size_t)255;
    return p;
  };
  unsigned short* enb = (unsigned short*)alloc((size_t)B * D * 2);
  unsigned short* cnb = (unsigned short*)alloc((size_t)C * D * 2);
  float* exx  = (float*)alloc((size_t)B * 4);
  float* cxx  = (float*)alloc((size_t)C * 4);
  float* hpos = (float*)alloc((size_t)B * 4);
  unsigned* mn0 = (unsigned*)alloc((size_t)B * 4);
  unsigned* mx0 = (unsigned*)alloc((size_t)B * 4);
  unsigned* fl0 = (unsigned*)alloc((size_t)B * 4);
  unsigned* mn1 = (unsigned*)alloc((size_t)B * 4);
  unsigned* mx1 = (unsigned*)alloc((size_t)B * 4);
  unsigned* fl1 = (unsigned*)alloc((size_t)B * 4);
  int* cnt     = (int*)alloc((size_t)C * 4);
  int* members = (int*)alloc((size_t)C * MMAX * 4);
  (void)ws_size; (void)n_in; (void)out_size;

  int mxBC = B > C ? B : C;
  k_init<<<(mxBC + 255) / 256, 256, 0, stream>>>(mn0, mx0, fl0, mn1, mx1, fl1, cnt, B, C);
  k_list<<<(B + 255) / 256, 256, (size_t)B * 4, stream>>>(labels, cnt, members, B, MMAX);

  if ((D & 2047) == 0 && (D >> 11) <= 2){
    if ((D >> 11) == 1){
      k_norm_emb<1><<<B, 256, 0, stream>>>(emb, enb, exx, D);
      k_centers<1><<<C, 256, 0, stream>>>(emb, cval, ccnt, cnt, members, cnb, cxx, D, MMAX);
    } else {
      k_norm_emb<2><<<B, 256, 0, stream>>>(emb, enb, exx, D);
      k_centers<2><<<C, 256, 0, stream>>>(emb, cval, ccnt, cnt, members, cnb, cxx, D, MMAX);
    }
  } else {
    k_norm_emb_gen<<<B, 256, 0, stream>>>(emb, enb, exx, D);
    k_centers_gen<<<C, 256, 0, stream>>>(emb, cval, ccnt, cnt, members, cnb, cxx, D, MMAX);
  }

  switch (D >> 9){   // D%512==0 fast paths; D=2048 -> 4
    case 1: k_hpos<1><<<B/4, 256, 0, stream>>>(enb, cnb, exx, cxx, labels, cnt, members, hpos, D, MMAX); break;
    case 2: k_hpos<2><<<B/4, 256, 0, stream>>>(enb, cnb, exx, cxx, labels, cnt, members, hpos, D, MMAX); break;
    case 3: k_hpos<3><<<B/4, 256, 0, stream>>>(enb, cnb, exx, cxx, labels, cnt, members, hpos, D, MMAX); break;
    case 4: k_hpos<4><<<B/4, 256, 0, stream>>>(enb, cnb, exx, cxx, labels, cnt, members, hpos, D, MMAX); break;
    case 6: k_hpos<6><<<B/4, 256, 0, stream>>>(enb, cnb, exx, cxx, labels, cnt, members, hpos, D, MMAX); break;
    case 8: k_hpos<8><<<B/4, 256, 0, stream>>>(enb, cnb, exx, cxx, labels, cnt, members, hpos, D, MMAX); break;
    default: k_hpos_gen<<<B/4, 256, 0, stream>>>(enb, cnb, exx, cxx, labels, cnt, members, hpos, D, MMAX); break;
  }

  int nby = B / 128, nCx = C / 128;
  int nTri = nby * (nby + 1) / 2;
  k_pd_all<<<nTri + nby * nCx, 256, 0, stream>>>(enb, cnb, exx, cxx, labels, hpos,
                                                 mn0, mx0, fl0, mn1, mx1, fl1,
                                                 D, nTri, nCx);
  k_final<<<1, 256, 0, stream>>>(hpos, mn0, mx0, fl0, mn1, mx1, fl1, margin, out, B);
}